// Round 13
// baseline (124.071 us; speedup 1.0000x reference)
//
#include <hip/hip_runtime.h>

// SLAYER SNN forward, MI355X. Round 26 = champion + DMA P1 (single variable).
// R12-round profile finally showed kf directly: 43.4-44.2 us, VGPR=88,
//   hbm ~0.1% -- latency-bound, 37% of total. kf has been 44-45 us through
//   EVERY restructure since R13; the invariant is P1's vbuf[100] register
//   prefetch. VGPR=88 proves the compiler never allocated the 100-deep
//   array (spill/strip-mine -> serialized element-wise load latency ~30 us).
// CHANGE (kf P1 only): u1 streamed via __builtin_amdgcn_global_load_lds
//   (width 4) into a 2-deep x 8-timestep LDS ring (16 KB). Per-wave
//   pipeline: issue chunk c+1 -> counted s_waitcnt vmcnt(8/4/0) (never
//   drain-0 mid-loop) -> scan chunk c from LDS -> publish f16 spike.
//   No VGPR staging, no barriers inside P1 (vmcnt is per-wave; each wave
//   owns its 64 cells). wreg loads vmcnt(0)-drained BEFORE the pipeline so
//   DMA counts are exact. LDS 52.8+16+8 = 77.2 KB -> still 2 blocks/CU.
// k0, k1, and kf's P2/scan2/dense are byte-identical to the champion
// (117.5/117.7/117.8 us reproduced on three containers).

#define DECAY 0.9048374180359595f   // exp(-1/10)

#define BAR_LGKM() asm volatile("s_waitcnt lgkmcnt(0)\n\ts_barrier" ::: "memory")
#define FENCE_LGKM() asm volatile("s_waitcnt lgkmcnt(0)" ::: "memory")

typedef __attribute__((ext_vector_type(8))) _Float16 half8;

#define GLOAD_LDS4(gp, lp) __builtin_amdgcn_global_load_lds(                    \
    (const __attribute__((address_space(1))) void*)(gp),                        \
    (__attribute__((address_space(3))) void*)(lp), 4, 0, 0)

// ---------------- k0: fold weights + zero out ----------------
// wl1[(cin*8 + e)*32 + c*8 + f]; wl2[c2*68 + cin*16 + e*4 + f]
__global__ __launch_bounds__(128) void k0_fold(const float* __restrict__ w1,
        const float* __restrict__ w2, const float* __restrict__ wp1,
        const float* __restrict__ wp2, float* __restrict__ wl1,
        float* __restrict__ wl2, float* __restrict__ out) {
    const int tid = threadIdx.x;
    out[blockIdx.x * 128 + tid] = 0.f;
    if (blockIdx.x != 0) return;
    const float p1 = wp1[0], p2 = wp2[0];
    for (int idx = tid; idx < 512; idx += 128) {
        const int f = idx & 7, c = (idx >> 3) & 3, e = (idx >> 5) & 7, cin = idx >> 8;
        const int cc = c * 2 + cin;
        int alo = e - 3; if (alo < 0) alo = 0;
        int ahi = e;     if (ahi > 4) ahi = 4;
        int blo = f - 3; if (blo < 0) blo = 0;
        int bhi = f;     if (bhi > 4) bhi = 4;
        float s = 0.f;
        for (int a = alo; a <= ahi; ++a)
            for (int b = blo; b <= bhi; ++b)
                s += w1[cc * 25 + a * 5 + b];
        wl1[(cin * 8 + e) * 32 + c * 8 + f] = s * p1;
    }
    for (int idx = tid; idx < 512; idx += 128) {
        const int c2 = idx & 7, f = (idx >> 3) & 3, e = (idx >> 5) & 3, cin = idx >> 7;
        int alo = e - 1; if (alo < 0) alo = 0;
        int ahi = e;     if (ahi > 2) ahi = 2;
        int blo = f - 1; if (blo < 0) blo = 0;
        int bhi = f;     if (bhi > 2) bhi = 2;
        float s = 0.f;
        for (int aa = alo; aa <= ahi; ++aa)
            for (int bb = blo; bb <= bhi; ++bb)
                s += w2[((c2 * 4 + cin) * 3 + aa) * 3 + bb];
        wl2[c2 * 68 + cin * 16 + e * 4 + f] = s * p2;
    }
}

// ---------------- k1: conv1+pool1, 8x8-tap stride-4 (R9, unchanged) ----------------
__global__ __launch_bounds__(64) void k1(const float* __restrict__ x,
        const float* __restrict__ wg, float* __restrict__ u1) {
    __shared__ __align__(16) float xs[2 * 1296];
    __shared__ __align__(16) float wl[512];
    const int lane = threadIdx.x;
    const int frame = blockIdx.x;                  // = n*100 + t (x is n-major)
    const int n = frame / 100, t = frame % 100;

    *(float4*)(wl + 4 * lane)       = *(const float4*)(wg + 4 * lane);
    *(float4*)(wl + 256 + 4 * lane) = *(const float4*)(wg + 256 + 4 * lane);

    #pragma unroll
    for (int m0 = 0; m0 < 128; m0 += 64) {
        const int m = m0 + lane;
        if (m < 72) {
            const int cin = m / 36, rem = m % 36;
            const int rr = rem / 9, q4 = rem % 9;
            const int pr = (rr == 0) ? 0 : (rr == 1) ? 9 : (rr == 2) ? 26 : 35;
            *(float4*)(xs + cin * 1296 + pr * 36 + q4 * 4) = make_float4(0.f, 0.f, 0.f, 0.f);
        }
    }
    #pragma unroll
    for (int m0 = 0; m0 < 192; m0 += 64) {
        const int m = m0 + lane;
        if (m < 144) {
            const int cin = m / 72, rem = m % 72;
            const int side = rem & 1, pr = rem >> 1;
            *(float2*)(xs + cin * 1296 + pr * 36 + side * 34) = make_float2(0.f, 0.f);
        }
    }
    const float4* xg = (const float4*)(x + (size_t)frame * 2048);
    #pragma unroll
    for (int q = 0; q < 8; ++q) {
        const int m = q * 64 + lane;
        const float4 v = xg[m];
        const int li = 4 * m;
        const int cin = li >> 10, row = (li >> 5) & 31, col = li & 31;
        const int r = row + 2;
        const int pr = (r & 3) * 9 + (r >> 2);
        float* d = xs + cin * 1296 + pr * 36 + col + 2;
        *(float2*)(d)     = make_float2(v.x, v.y);
        *(float2*)(d + 2) = make_float2(v.z, v.w);
    }
    FENCE_LGKM();

    const int cp = lane >> 5;
    const int i  = (lane >> 2) & 7;
    const int jh = (lane >> 1) & 1;
    const int eh = lane & 1;

    float acc[2][4] = {{0.f, 0.f, 0.f, 0.f}, {0.f, 0.f, 0.f, 0.f}};
    const float* tb = xs + (i + eh) * 36 + jh * 16;
    #pragma unroll
    for (int cin = 0; cin < 2; ++cin) {
        #pragma unroll
        for (int et = 0; et < 4; ++et) {
            const int ro = cin * 1296 + et * 9 * 36;
            float xr[20];
            #pragma unroll
            for (int b = 0; b < 5; ++b)
                *(float4*)(xr + 4 * b) = *(const float4*)(tb + ro + 4 * b);
            float wv[16];
            const float* wp = wl + (cin * 8 + eh * 4 + et) * 32 + cp * 16;
            #pragma unroll
            for (int q = 0; q < 4; ++q)
                *(float4*)(wv + 4 * q) = *(const float4*)(wp + 4 * q);
            #pragma unroll
            for (int cl = 0; cl < 2; ++cl) {
                #pragma unroll
                for (int jj = 0; jj < 4; ++jj) {
                    const int o = 4 * jj;
                    acc[cl][jj] += xr[o]*wv[cl*8]     + xr[o+1]*wv[cl*8+1]
                                 + xr[o+2]*wv[cl*8+2] + xr[o+3]*wv[cl*8+3]
                                 + xr[o+4]*wv[cl*8+4] + xr[o+5]*wv[cl*8+5]
                                 + xr[o+6]*wv[cl*8+6] + xr[o+7]*wv[cl*8+7];
                }
            }
        }
    }
    #pragma unroll
    for (int cl = 0; cl < 2; ++cl)
        #pragma unroll
        for (int jj = 0; jj < 4; ++jj)
            acc[cl][jj] += __shfl_xor(acc[cl][jj], 1);

    const float o0 = eh ? acc[1][0] : acc[0][0];
    const float o1 = eh ? acc[1][1] : acc[0][1];
    const float o2 = eh ? acc[1][2] : acc[0][2];
    const float o3 = eh ? acc[1][3] : acc[0][3];
    *(float4*)(u1 + (size_t)t * 16384 + n * 256 + (2 * cp + eh) * 64 + i * 8 + jh * 4) =
        make_float4(o0, o1, o2, o3);
}

// ---------------- kf: DMA scan1 + conv2(oct) + scan2 + dense ----------------
// grid 512 x 256: oct = (bid>>3)&7, n = (bid&7)*8 + (bid>>6)  (bijective;
// the 8 oct siblings of each n share bid%8 -> one XCD's L2 for the u1 slice).
// P1: u1 -> LDS via global_load_lds width-4, 2x8-timestep ring, per-wave
// counted vmcnt pipeline. ls1h: 100 x 264 halfs (52.8 KB). ubuf: 16 KB.
// ls2: 100 x 20 floats (8 KB). Total 77.2 KB -> 2 blocks/CU.
__global__ __launch_bounds__(256, 2) void kf(const float* __restrict__ u1,
        const float* __restrict__ wl2g, const float* __restrict__ lw,
        float* __restrict__ out) {
    __shared__ __align__(16) _Float16 ls1h[100 * 264];  // 52.8 KB
    __shared__ __align__(16) float    ubuf[2][8 * 256]; // 16.0 KB DMA ring
    __shared__ __align__(16) float    ls2[100 * 20];    //  8.0 KB
    const int tid = threadIdx.x;
    const int bid = blockIdx.x;
    const int n   = (bid & 7) * 8 + (bid >> 6);   // XCD-aware, bijective
    const int oct = (bid >> 3) & 7;               // c2 channel
    const int wave = tid >> 6, l64 = tid & 63;
    const float a = DECAY;

    // P2 mapping: thread = (sub, i2, jhp); 8 threads/slot, 32 slots/pass
    const int sub = tid >> 3, l8 = tid & 7;
    const int i2 = l8 >> 1, jhp = l8 & 1;

    float4 wreg[16];   // [cin*4+e] = folded taps f0..3 for channel oct
    {
        const float* wbase = wl2g + oct * 68;
        #pragma unroll
        for (int q = 0; q < 16; ++q)
            wreg[q] = *(const float4*)(wbase + (q >> 2) * 16 + (q & 3) * 4);
    }
    // Drain wreg loads so the DMA pipeline's vmcnt counts are exact.
    asm volatile("s_waitcnt vmcnt(0)" ::: "memory");

    // --- P1: DMA pipeline. chunk c = timesteps 8c..8c+7 (c=12: 4 steps). ---
    // Wave w owns cells w*64..w*64+63; DMA lptr is wave-uniform, lane
    // deposits its 4 B at lptr + lane*4 -> ubuf[buf][kk*256 + tid].
    {
        const float* usrc = u1 + n * 256 + tid;   // per-lane global column
        float* const wbase0 = &ubuf[0][wave * 64];
        float* const wbase1 = &ubuf[1][wave * 64];

        // prologue: issue chunk 0
        #pragma unroll
        for (int kk = 0; kk < 8; ++kk)
            GLOAD_LDS4(usrc + (size_t)kk * 16384, wbase0 + kk * 256);

        float psp = 0.f, rr = 0.f;
        #pragma unroll 1
        for (int c = 0; c < 13; ++c) {
            // issue chunk c+1 into the other buffer
            if (c < 11) {
                float* const dst = ((c + 1) & 1) ? wbase1 : wbase0;
                const int kb = (c + 1) * 8;
                #pragma unroll
                for (int kk = 0; kk < 8; ++kk)
                    GLOAD_LDS4(usrc + (size_t)(kb + kk) * 16384, dst + kk * 256);
            } else if (c == 11) {
                float* const dst = wbase0;        // chunk 12 -> buf 0
                #pragma unroll
                for (int kk = 0; kk < 4; ++kk)
                    GLOAD_LDS4(usrc + (size_t)(96 + kk) * 16384, dst + kk * 256);
            }
            // counted wait: chunk c landed, chunk c+1 stays in flight
            if (c < 11)      asm volatile("s_waitcnt vmcnt(8)" ::: "memory");
            else if (c < 12) asm volatile("s_waitcnt vmcnt(4)" ::: "memory");
            else             asm volatile("s_waitcnt vmcnt(0)" ::: "memory");
            __builtin_amdgcn_sched_barrier(0);

            // scan chunk c from LDS, publish f16 spikes
            const float* src = (c & 1) ? &ubuf[1][0] : &ubuf[0][0];
            const int cnt = (c == 12) ? 4 : 8;
            #pragma unroll
            for (int kk = 0; kk < 8; ++kk) {
                if (kk < cnt) {
                    const float v = src[kk * 256 + tid];
                    psp = a * psp + v;
                    const float vv = psp - rr;
                    const float s = (vv >= 1.f) ? 1.f : 0.f;
                    rr = a * (rr + s);
                    ls1h[(c * 8 + kk) * 264 + tid] = (_Float16)s;  // 0/1 exact
                }
            }
        }
    }
    BAR_LGKM();

    // --- P2: conv2 (1 channel), 4 predicated passes x 32 slots ---
    #pragma unroll 1
    for (int pass = 0; pass < 4; ++pass) {
        const int slot = sub + 32 * pass;
        if (slot < 100) {
            const _Float16* sb = ls1h + slot * 264;
            float acc0 = 0.f, acc1 = 0.f;
            #pragma unroll
            for (int cin = 0; cin < 4; ++cin) {
                #pragma unroll
                for (int e = 0; e < 4; ++e) {
                    const int ri = 2 * i2 + e - 1;            // input row, -1..8
                    const int rc = (ri < 0) ? 0 : (ri > 7 ? 7 : ri);
                    const bool rok = (ri >= 0) && (ri <= 7);
                    const half8 hv = *(const half8*)(sb + cin * 64 + rc * 8);
                    float rr8[8];
                    #pragma unroll
                    for (int m = 0; m < 8; ++m) rr8[m] = (float)hv[m];
                    // xr matches pad reads: jhp=0 -> {0,r0..r4}; jhp=1 -> {r3..r7,0}
                    float xr[6];
                    xr[0] = jhp ? rr8[3] : 0.0f;
                    xr[1] = jhp ? rr8[4] : rr8[0];
                    xr[2] = jhp ? rr8[5] : rr8[1];
                    xr[3] = jhp ? rr8[6] : rr8[2];
                    xr[4] = jhp ? rr8[7] : rr8[3];
                    xr[5] = jhp ? 0.0f   : rr8[4];
                    if (!rok) {
                        #pragma unroll
                        for (int m = 0; m < 6; ++m) xr[m] = 0.0f;
                    }
                    const float4 wf = wreg[cin * 4 + e];
                    acc0 += xr[0] * wf.x; acc0 += xr[1] * wf.y;
                    acc0 += xr[2] * wf.z; acc0 += xr[3] * wf.w;
                    acc1 += xr[2] * wf.x; acc1 += xr[3] * wf.y;
                    acc1 += xr[4] * wf.z; acc1 += xr[5] * wf.w;
                }
            }
            // cell index within channel = i2*4 + j  (j = 2jhp, 2jhp+1)
            *(float2*)(ls2 + slot * 20 + i2 * 4 + 2 * jhp) =
                make_float2(acc0, acc1);
        }
    }
    BAR_LGKM();

    // --- scan2: wave0 lanes 0..15 (one per cell), register-resident ---
    if (wave == 0 && l64 < 16) {
        float ub[100];
        #pragma unroll
        for (int k = 0; k < 100; ++k) ub[k] = ls2[k * 20 + l64];
        float psp2 = 0.f, rr2 = 0.f;
        #pragma unroll
        for (int k = 0; k < 100; ++k) {
            psp2 = a * psp2 + ub[k];
            const float vv = psp2 - rr2;
            const float s = (vv >= 1.f) ? 1.f : 0.f;
            rr2 = a * (rr2 + s);
            ls2[k * 20 + l64] = s;     // store-only publish (no RMW chain)
        }
    }
    BAR_LGKM();

    // --- dense: all waves; thread (t,o) dots 16 spikes x 16 weights ---
    if (tid < 200) {
        const int t = tid >> 1, o = tid & 1;
        const float* srow = ls2 + t * 20;
        const float* wrow = lw + o * 128 + oct * 16;   // contiguous 16 cells
        const float4 s0 = *(const float4*)(srow);
        const float4 s1 = *(const float4*)(srow + 4);
        const float4 s2 = *(const float4*)(srow + 8);
        const float4 s3 = *(const float4*)(srow + 12);
        const float4 w0 = *(const float4*)(wrow);
        const float4 w1 = *(const float4*)(wrow + 4);
        const float4 w2 = *(const float4*)(wrow + 8);
        const float4 w3 = *(const float4*)(wrow + 12);
        float v = 0.f;
        v += s0.x * w0.x; v += s0.y * w0.y; v += s0.z * w0.z; v += s0.w * w0.w;
        v += s1.x * w1.x; v += s1.y * w1.y; v += s1.z * w1.z; v += s1.w * w1.w;
        v += s2.x * w2.x; v += s2.y * w2.y; v += s2.z * w2.z; v += s2.w * w2.w;
        v += s3.x * w3.x; v += s3.y * w3.y; v += s3.z * w3.z; v += s3.w * w3.w;
        atomicAdd(&out[n * 200 + t * 2 + o], v);
    }
}

extern "C" void kernel_launch(void* const* d_in, const int* in_sizes, int n_in,
                              void* d_out, int out_size, void* d_ws, size_t ws_size,
                              hipStream_t stream) {
    const float* x   = (const float*)d_in[0];
    const float* w1  = (const float*)d_in[1];
    const float* w2  = (const float*)d_in[2];
    const float* lw  = (const float*)d_in[3];
    const float* wp1 = (const float*)d_in[4];
    const float* wp2 = (const float*)d_in[5];

    float* u1  = (float*)d_ws;           // 1,638,400 floats
    float* wl1 = u1 + 1638400;           //       512 floats
    float* wl2 = wl1 + 512;              //       544 floats
    float* out = (float*)d_out;          // (64,100,2) = 12800 floats

    k0_fold<<<100, 128, 0, stream>>>(w1, w2, wp1, wp2, wl1, wl2, out);
    k1<<<6400, 64, 0, stream>>>(x, wl1, u1);
    kf<<<512, 256, 0, stream>>>(u1, wl2, lw, out);
}

// Round 14
// 117.001 us; speedup vs baseline: 1.0604x; 1.0604x over previous
//
#include <hip/hip_runtime.h>

// SLAYER SNN forward, MI355X. Round 27 = FINAL: restore champion (R16/R22/R25).
// Ledger: champion reproduces at 117.5/117.7/117.8 us on three containers
//   (+-0.3). EIGHT consecutive theory-driven variants all regressed:
//   R17 coop-fusion +76; R18 n-major+in-k1-fold +11.5; R19 k_s split +9.4;
//   R20 rolling-P1(+n-major) +8.6; R21 2-launch +26; R23 rolling-P1 clean
//   +12.6; R24 t-minor layout +8.9; R26 DMA-P1 (global_load_lds ring) +6.4.
// Round-12's "kf=44us" rows were a counter-replay artifact (NaN FETCH,
//   serialized instrumentation pass) -- same source measured <41us in R22.
// Measured composition of 117.5: ~42us harness workspace fill (80% HBM) +
//   ~13us launch/graph overhead (R17: 194-138.7) + ~62us kernels/gaps with
//   VALUBusy 8-10%, HBM <=4% -- small latency-bound kernels in a sharp local
//   minimum; every probed neighborhood direction costs 6-76us.
// Structure: k0 (fold wl1+wl2, zero out) -> k1 (R9 conv1+pool1, t-major u1)
//   -> kf (oct-split: full-prefetch scan1 -> f16 spikes, conv2, register
//   scan2, parallel dense, XCD-swizzled n, 2 blocks/CU).

#define DECAY 0.9048374180359595f   // exp(-1/10)

#define BAR_LGKM() asm volatile("s_waitcnt lgkmcnt(0)\n\ts_barrier" ::: "memory")
#define FENCE_LGKM() asm volatile("s_waitcnt lgkmcnt(0)" ::: "memory")

typedef __attribute__((ext_vector_type(8))) _Float16 half8;

// ---------------- k0: fold weights + zero out ----------------
// wl1[(cin*8 + e)*32 + c*8 + f]; wl2[c2*68 + cin*16 + e*4 + f]
__global__ __launch_bounds__(128) void k0_fold(const float* __restrict__ w1,
        const float* __restrict__ w2, const float* __restrict__ wp1,
        const float* __restrict__ wp2, float* __restrict__ wl1,
        float* __restrict__ wl2, float* __restrict__ out) {
    const int tid = threadIdx.x;
    out[blockIdx.x * 128 + tid] = 0.f;
    if (blockIdx.x != 0) return;
    const float p1 = wp1[0], p2 = wp2[0];
    for (int idx = tid; idx < 512; idx += 128) {
        const int f = idx & 7, c = (idx >> 3) & 3, e = (idx >> 5) & 7, cin = idx >> 8;
        const int cc = c * 2 + cin;
        int alo = e - 3; if (alo < 0) alo = 0;
        int ahi = e;     if (ahi > 4) ahi = 4;
        int blo = f - 3; if (blo < 0) blo = 0;
        int bhi = f;     if (bhi > 4) bhi = 4;
        float s = 0.f;
        for (int a = alo; a <= ahi; ++a)
            for (int b = blo; b <= bhi; ++b)
                s += w1[cc * 25 + a * 5 + b];
        wl1[(cin * 8 + e) * 32 + c * 8 + f] = s * p1;
    }
    for (int idx = tid; idx < 512; idx += 128) {
        const int c2 = idx & 7, f = (idx >> 3) & 3, e = (idx >> 5) & 3, cin = idx >> 7;
        int alo = e - 1; if (alo < 0) alo = 0;
        int ahi = e;     if (ahi > 2) ahi = 2;
        int blo = f - 1; if (blo < 0) blo = 0;
        int bhi = f;     if (bhi > 2) bhi = 2;
        float s = 0.f;
        for (int aa = alo; aa <= ahi; ++aa)
            for (int bb = blo; bb <= bhi; ++bb)
                s += w2[((c2 * 4 + cin) * 3 + aa) * 3 + bb];
        wl2[c2 * 68 + cin * 16 + e * 4 + f] = s * p2;
    }
}

// ---------------- k1: conv1+pool1, 8x8-tap stride-4 (R9, unchanged) ----------------
__global__ __launch_bounds__(64) void k1(const float* __restrict__ x,
        const float* __restrict__ wg, float* __restrict__ u1) {
    __shared__ __align__(16) float xs[2 * 1296];
    __shared__ __align__(16) float wl[512];
    const int lane = threadIdx.x;
    const int frame = blockIdx.x;                  // = n*100 + t (x is n-major)
    const int n = frame / 100, t = frame % 100;

    *(float4*)(wl + 4 * lane)       = *(const float4*)(wg + 4 * lane);
    *(float4*)(wl + 256 + 4 * lane) = *(const float4*)(wg + 256 + 4 * lane);

    #pragma unroll
    for (int m0 = 0; m0 < 128; m0 += 64) {
        const int m = m0 + lane;
        if (m < 72) {
            const int cin = m / 36, rem = m % 36;
            const int rr = rem / 9, q4 = rem % 9;
            const int pr = (rr == 0) ? 0 : (rr == 1) ? 9 : (rr == 2) ? 26 : 35;
            *(float4*)(xs + cin * 1296 + pr * 36 + q4 * 4) = make_float4(0.f, 0.f, 0.f, 0.f);
        }
    }
    #pragma unroll
    for (int m0 = 0; m0 < 192; m0 += 64) {
        const int m = m0 + lane;
        if (m < 144) {
            const int cin = m / 72, rem = m % 72;
            const int side = rem & 1, pr = rem >> 1;
            *(float2*)(xs + cin * 1296 + pr * 36 + side * 34) = make_float2(0.f, 0.f);
        }
    }
    const float4* xg = (const float4*)(x + (size_t)frame * 2048);
    #pragma unroll
    for (int q = 0; q < 8; ++q) {
        const int m = q * 64 + lane;
        const float4 v = xg[m];
        const int li = 4 * m;
        const int cin = li >> 10, row = (li >> 5) & 31, col = li & 31;
        const int r = row + 2;
        const int pr = (r & 3) * 9 + (r >> 2);
        float* d = xs + cin * 1296 + pr * 36 + col + 2;
        *(float2*)(d)     = make_float2(v.x, v.y);
        *(float2*)(d + 2) = make_float2(v.z, v.w);
    }
    FENCE_LGKM();

    const int cp = lane >> 5;
    const int i  = (lane >> 2) & 7;
    const int jh = (lane >> 1) & 1;
    const int eh = lane & 1;

    float acc[2][4] = {{0.f, 0.f, 0.f, 0.f}, {0.f, 0.f, 0.f, 0.f}};
    const float* tb = xs + (i + eh) * 36 + jh * 16;
    #pragma unroll
    for (int cin = 0; cin < 2; ++cin) {
        #pragma unroll
        for (int et = 0; et < 4; ++et) {
            const int ro = cin * 1296 + et * 9 * 36;
            float xr[20];
            #pragma unroll
            for (int b = 0; b < 5; ++b)
                *(float4*)(xr + 4 * b) = *(const float4*)(tb + ro + 4 * b);
            float wv[16];
            const float* wp = wl + (cin * 8 + eh * 4 + et) * 32 + cp * 16;
            #pragma unroll
            for (int q = 0; q < 4; ++q)
                *(float4*)(wv + 4 * q) = *(const float4*)(wp + 4 * q);
            #pragma unroll
            for (int cl = 0; cl < 2; ++cl) {
                #pragma unroll
                for (int jj = 0; jj < 4; ++jj) {
                    const int o = 4 * jj;
                    acc[cl][jj] += xr[o]*wv[cl*8]     + xr[o+1]*wv[cl*8+1]
                                 + xr[o+2]*wv[cl*8+2] + xr[o+3]*wv[cl*8+3]
                                 + xr[o+4]*wv[cl*8+4] + xr[o+5]*wv[cl*8+5]
                                 + xr[o+6]*wv[cl*8+6] + xr[o+7]*wv[cl*8+7];
                }
            }
        }
    }
    #pragma unroll
    for (int cl = 0; cl < 2; ++cl)
        #pragma unroll
        for (int jj = 0; jj < 4; ++jj)
            acc[cl][jj] += __shfl_xor(acc[cl][jj], 1);

    const float o0 = eh ? acc[1][0] : acc[0][0];
    const float o1 = eh ? acc[1][1] : acc[0][1];
    const float o2 = eh ? acc[1][2] : acc[0][2];
    const float o3 = eh ? acc[1][3] : acc[0][3];
    *(float4*)(u1 + (size_t)t * 16384 + n * 256 + (2 * cp + eh) * 64 + i * 8 + jh * 4) =
        make_float4(o0, o1, o2, o3);
}

// ---------------- kf: fused scan1 + conv2(oct) + scan2 + dense ----------------
// grid 512 x 256: oct = (bid>>3)&7, n = (bid&7)*8 + (bid>>6)  (bijective;
// the 8 oct siblings of each n share bid%8 -> one XCD's L2 for the u1 slice).
// ls1h: 100 slots x 264 halfs (52.8 KB, row 528 B = 33x16 -> b128-aligned).
// ls2 : 100 slots x 20 floats (8 KB, row 80 B -> b128-aligned); cells [i*4+j].
__global__ __launch_bounds__(256, 2) void kf(const float* __restrict__ u1,
        const float* __restrict__ wl2g, const float* __restrict__ lw,
        float* __restrict__ out) {
    __shared__ __align__(16) _Float16 ls1h[100 * 264];  // 52.8 KB
    __shared__ __align__(16) float    ls2[100 * 20];    //  8.0 KB
    const int tid = threadIdx.x;
    const int bid = blockIdx.x;
    const int n   = (bid & 7) * 8 + (bid >> 6);   // XCD-aware, bijective
    const int oct = (bid >> 3) & 7;               // c2 channel
    const int wave = tid >> 6, l64 = tid & 63;
    const float a = DECAY;

    const float* up = u1 + n * 256 + tid;

    // P2 mapping: thread = (sub, i2, jhp); 8 threads/slot, 32 slots/pass
    const int sub = tid >> 3, l8 = tid & 7;
    const int i2 = l8 >> 1, jhp = l8 & 1;

    float4 wreg[16];   // [cin*4+e] = folded taps f0..3 for channel oct
    {
        const float* wbase = wl2g + oct * 68;
        #pragma unroll
        for (int q = 0; q < 16; ++q)
            wreg[q] = *(const float4*)(wbase + (q >> 2) * 16 + (q & 3) * 4);
    }

    // --- P1: load all 100 u (coalesced, pipelined), scan1, publish f16 ---
    float vbuf[100];
    #pragma unroll
    for (int k = 0; k < 100; ++k) vbuf[k] = up[(size_t)k * 16384];
    {
        float psp = 0.f, rr = 0.f;
        #pragma unroll
        for (int k = 0; k < 100; ++k) {
            psp = a * psp + vbuf[k];
            const float vv = psp - rr;
            const float s = (vv >= 1.f) ? 1.f : 0.f;
            rr = a * (rr + s);
            ls1h[k * 264 + tid] = (_Float16)s;   // 0/1 exact in f16
        }
    }
    BAR_LGKM();

    // --- P2: conv2 (1 channel), 4 predicated passes x 32 slots ---
    #pragma unroll 1
    for (int pass = 0; pass < 4; ++pass) {
        const int slot = sub + 32 * pass;
        if (slot < 100) {
            const _Float16* sb = ls1h + slot * 264;
            float acc0 = 0.f, acc1 = 0.f;
            #pragma unroll
            for (int cin = 0; cin < 4; ++cin) {
                #pragma unroll
                for (int e = 0; e < 4; ++e) {
                    const int ri = 2 * i2 + e - 1;            // input row, -1..8
                    const int rc = (ri < 0) ? 0 : (ri > 7 ? 7 : ri);
                    const bool rok = (ri >= 0) && (ri <= 7);
                    const half8 hv = *(const half8*)(sb + cin * 64 + rc * 8);
                    float rr8[8];
                    #pragma unroll
                    for (int m = 0; m < 8; ++m) rr8[m] = (float)hv[m];
                    // xr matches pad reads: jhp=0 -> {0,r0..r4}; jhp=1 -> {r3..r7,0}
                    float xr[6];
                    xr[0] = jhp ? rr8[3] : 0.0f;
                    xr[1] = jhp ? rr8[4] : rr8[0];
                    xr[2] = jhp ? rr8[5] : rr8[1];
                    xr[3] = jhp ? rr8[6] : rr8[2];
                    xr[4] = jhp ? rr8[7] : rr8[3];
                    xr[5] = jhp ? 0.0f   : rr8[4];
                    if (!rok) {
                        #pragma unroll
                        for (int m = 0; m < 6; ++m) xr[m] = 0.0f;
                    }
                    const float4 wf = wreg[cin * 4 + e];
                    acc0 += xr[0] * wf.x; acc0 += xr[1] * wf.y;
                    acc0 += xr[2] * wf.z; acc0 += xr[3] * wf.w;
                    acc1 += xr[2] * wf.x; acc1 += xr[3] * wf.y;
                    acc1 += xr[4] * wf.z; acc1 += xr[5] * wf.w;
                }
            }
            // cell index within channel = i2*4 + j  (j = 2jhp, 2jhp+1)
            *(float2*)(ls2 + slot * 20 + i2 * 4 + 2 * jhp) =
                make_float2(acc0, acc1);
        }
    }
    BAR_LGKM();

    // --- scan2: wave0 lanes 0..15 (one per cell), register-resident ---
    if (wave == 0 && l64 < 16) {
        float ub[100];
        #pragma unroll
        for (int k = 0; k < 100; ++k) ub[k] = ls2[k * 20 + l64];
        float psp2 = 0.f, rr2 = 0.f;
        #pragma unroll
        for (int k = 0; k < 100; ++k) {
            psp2 = a * psp2 + ub[k];
            const float vv = psp2 - rr2;
            const float s = (vv >= 1.f) ? 1.f : 0.f;
            rr2 = a * (rr2 + s);
            ls2[k * 20 + l64] = s;     // store-only publish (no RMW chain)
        }
    }
    BAR_LGKM();

    // --- dense: all waves; thread (t,o) dots 16 spikes x 16 weights ---
    if (tid < 200) {
        const int t = tid >> 1, o = tid & 1;
        const float* srow = ls2 + t * 20;
        const float* wrow = lw + o * 128 + oct * 16;   // contiguous 16 cells
        const float4 s0 = *(const float4*)(srow);
        const float4 s1 = *(const float4*)(srow + 4);
        const float4 s2 = *(const float4*)(srow + 8);
        const float4 s3 = *(const float4*)(srow + 12);
        const float4 w0 = *(const float4*)(wrow);
        const float4 w1 = *(const float4*)(wrow + 4);
        const float4 w2 = *(const float4*)(wrow + 8);
        const float4 w3 = *(const float4*)(wrow + 12);
        float v = 0.f;
        v += s0.x * w0.x; v += s0.y * w0.y; v += s0.z * w0.z; v += s0.w * w0.w;
        v += s1.x * w1.x; v += s1.y * w1.y; v += s1.z * w1.z; v += s1.w * w1.w;
        v += s2.x * w2.x; v += s2.y * w2.y; v += s2.z * w2.z; v += s2.w * w2.w;
        v += s3.x * w3.x; v += s3.y * w3.y; v += s3.z * w3.z; v += s3.w * w3.w;
        atomicAdd(&out[n * 200 + t * 2 + o], v);
    }
}

extern "C" void kernel_launch(void* const* d_in, const int* in_sizes, int n_in,
                              void* d_out, int out_size, void* d_ws, size_t ws_size,
                              hipStream_t stream) {
    const float* x   = (const float*)d_in[0];
    const float* w1  = (const float*)d_in[1];
    const float* w2  = (const float*)d_in[2];
    const float* lw  = (const float*)d_in[3];
    const float* wp1 = (const float*)d_in[4];
    const float* wp2 = (const float*)d_in[5];

    float* u1  = (float*)d_ws;           // 1,638,400 floats
    float* wl1 = u1 + 1638400;           //       512 floats
    float* wl2 = wl1 + 512;              //       544 floats
    float* out = (float*)d_out;          // (64,100,2) = 12800 floats

    k0_fold<<<100, 128, 0, stream>>>(w1, w2, wp1, wp2, wl1, wl2, out);
    k1<<<6400, 64, 0, stream>>>(x, wl1, u1);
    kf<<<512, 256, 0, stream>>>(u1, wl2, lw, out);
}